// Round 10
// baseline (247.170 us; speedup 1.0000x reference)
//
#include <hip/hip_runtime.h>
#include <hip/hip_fp16.h>
#include <stdint.h>

#define EPS_BN 1e-5f

constexpr int Fn = 32;    // frames
constexpr int Pn = 64;    // peds per frame
constexpr int Bn = 2048;  // batch
constexpr int Hn = 128;   // h_dim
constexpr int En = 64;    // embed dim
constexpr int Mn = 512;   // GEMM K
constexpr int Dn = 1024;  // GEMM N

using f16x8   = __attribute__((ext_vector_type(8))) _Float16;
using f32x16  = __attribute__((ext_vector_type(16))) float;

static __device__ __forceinline__ unsigned short hfbits(float f) {
  return __builtin_bit_cast(unsigned short, __float2half(f));
}

// async 16B/lane global -> LDS (LDS base wave-uniform; HW adds lane*16)
static __device__ __forceinline__ void dma16(const uint4* g, const uint4* l) {
  __builtin_amdgcn_global_load_lds(
      (const __attribute__((address_space(1))) unsigned int*)g,
      (__attribute__((address_space(3))) unsigned int*)l, 16, 0, 0);
}

// packed fp16 max: one VOP3P instruction (ROCm header lacks __hmax2)
static __device__ __forceinline__ uint32_t pkmax(uint32_t a, uint32_t b) {
  uint32_t r;
  asm("v_pk_max_f16 %0, %1, %2" : "=v"(r) : "v"(a), "v"(b));
  return r;
}

// r0/r1 = fp16 max(a0,q), max(a1,q): 8 instructions total.
static __device__ __forceinline__ void mk2(uint4 a0, uint4 a1, uint4 q,
                                           f16x8& r0, f16x8& r1) {
  uint4 x0, x1;
#pragma unroll
  for (int v = 0; v < 4; ++v) {
    uint32_t qw = ((const uint32_t*)&q)[v];
    ((uint32_t*)&x0)[v] = pkmax(((const uint32_t*)&a0)[v], qw);
    ((uint32_t*)&x1)[v] = pkmax(((const uint32_t*)&a1)[v], qw);
  }
  r0 = __builtin_bit_cast(f16x8, x0);
  r1 = __builtin_bit_cast(f16x8, x1);
}

// ---------------------------------------------------------------------------
// prep_all: 656 blocks x 512 threads (unchanged).
// ---------------------------------------------------------------------------
__global__ void prep_all(const float* __restrict__ hs, const float* __restrict__ pos,
                         const float* __restrict__ We, const float* __restrict__ be,
                         const float* __restrict__ W1, const float* __restrict__ b1,
                         const float* __restrict__ g1, const float* __restrict__ beta1,
                         const float* __restrict__ rm1, const float* __restrict__ rv1,
                         const float* __restrict__ W2, const float* __restrict__ b2,
                         const float* __restrict__ g2, const float* __restrict__ beta2,
                         const float* __restrict__ rm2, const float* __restrict__ rv2,
                         __half* __restrict__ Agb, __half* __restrict__ Qgb,
                         uint4* __restrict__ W2g, float* __restrict__ G0,
                         float* __restrict__ G1, float* __restrict__ c2) {
  __shared__ float smem[64 * 65];
  int bid = blockIdx.x, t = threadIdx.x;
  if (bid < 512) {
    // ---- Ag/Qg for 4 batch rows, no LDS ----
    int rb = bid * 4, m = t;
    float w0 = 0.f, w1 = 0.f, c = 0.f;
    for (int e = 0; e < En; ++e) {
      float w = W1[e * Mn + m];
      w0 += We[e] * w; w1 += We[En + e] * w; c += be[e] * w;
    }
    c += b1[m];
    float s  = g1[m] * rsqrtf(rv1[m] + EPS_BN);
    float tt = beta1[m] - rm1[m] * s;
    float acc[4];
#pragma unroll
    for (int ri = 0; ri < 4; ++ri) acc[ri] = c;
#pragma unroll 4
    for (int e = 0; e < Hn; ++e) {
      float w = W1[(En + e) * Mn + m];
#pragma unroll
      for (int ri = 0; ri < 4; ++ri)
        acc[ri] += hs[(rb + ri) * Hn + e] * w;   // uniform addr -> s_load
    }
#pragma unroll
    for (int ri = 0; ri < 4; ++ri) {
      float q = pos[(rb + ri) * 2] * w0 + pos[(rb + ri) * 2 + 1] * w1;  // uniform
      Agb[(rb + ri) * Mn + m] = __float2half((acc[ri] + q) * s + tt);
      Qgb[(rb + ri) * Mn + m] = __float2half(q * s);
    }
  } else if (bid < 640) {
    // ---- W2 -> 32-col B-fragment granules (s2 folded), fp16 ----
    int b2i = bid - 512;                 // 0..127
    int d0 = (b2i & 15) * 64, k0 = (b2i >> 4) * 64;
    int col = t & 63, row8 = t >> 6;
#pragma unroll
    for (int rr = 0; rr < 8; ++rr) {
      int row = rr * 8 + row8;
      smem[row * 65 + col] = W2[(k0 + row) * Dn + d0 + col];  // [k_local][d_local]
    }
    __syncthreads();
    int lane = t & 63, q8 = t >> 6;
    int sel_n = q8 & 1, sel_ks = q8 >> 1;
    int dl = sel_n * 32 + (lane & 31), d = d0 + dl;
    float sf = g2[d] * rsqrtf(rv2[d] + EPS_BN);
    int kb = sel_ks * 16 + (lane >> 5) * 8;
    uint32_t wd[4];
#pragma unroll
    for (int h = 0; h < 4; ++h) {
      uint32_t u0 = hfbits(smem[(kb + 2 * h) * 65 + dl] * sf);
      uint32_t u1 = hfbits(smem[(kb + 2 * h + 1) * 65 + dl] * sf);
      wd[h] = u0 | (u1 << 16);
    }
    int n32 = (d0 >> 5) + sel_n;
    int ks  = (k0 >> 4) + sel_ks;
    W2g[(n32 * 32 + ks) * 64 + lane] = (uint4){wd[0], wd[1], wd[2], wd[3]};
  } else {
    // ---- G slice (64 d-cols) + c2 ----
    int gb = bid - 640;           // 0..15
    int d0g = gb * 64;
    float* wr0 = smem;            // [0,512)
    float* wr1 = smem + 512;      // [512,1024)
    {
      int m = t;
      float w0 = 0.f, w1 = 0.f;
      for (int e = 0; e < En; ++e) {
        float w = W1[e * Mn + m];
        w0 += We[e] * w; w1 += We[En + e] * w;
      }
      float s = g1[m] * rsqrtf(rv1[m] + EPS_BN);
      wr0[m] = w0 * s; wr1[m] = w1 * s;
    }
    __syncthreads();
    int dl = t & 63, part = t >> 6;   // 8 m-parts x 64 d
    float p0 = 0.f, p1 = 0.f;
#pragma unroll 4
    for (int mm = 0; mm < 64; ++mm) {
      int m = part * 64 + mm;
      float wv = W2[m * Dn + d0g + dl];
      p0 += wr0[m] * wv; p1 += wr1[m] * wv;
    }
    float* pr = smem + 1024;
    pr[part * 64 + dl] = p0;
    pr[512 + part * 64 + dl] = p1;
    __syncthreads();
    if (t < 128) {
      int which = t >> 6, dd = d0g + (t & 63);
      float s2v = g2[dd] * rsqrtf(rv2[dd] + EPS_BN);
      float sum = 0.f;
#pragma unroll
      for (int pp = 0; pp < 8; ++pp) sum += pr[which * 512 + pp * 64 + (t & 63)];
      (which ? G1 : G0)[dd] = sum * s2v;
      if (which == 0) c2[dd] = b2[dd] * s2v + beta2[dd] - rm2[dd] * s2v;
    }
  }
}

// ---------------------------------------------------------------------------
// gemm_pool R10: occupancy-first retile. Wave = 1i x 64j x 64d (2jf x 2nf):
// acc = 4 x f32x16 = 64 AGPR -> ~120 unified regs -> 4 waves/SIMD (2x R4).
// Block = 4 waves (4i x 64j x 64d); LDS = A 8K dbuf + B 8K dbuf + Q 4K =
// 36KB -> 4 blocks/CU, 16 waves/CU. Mechanism: R4's 50% MfmaUtil with no
// saturated pipe = stall-bound at 2 waves/SIMD (212 regs); every graft at
// that occupancy was null (R3/R8/R9). 2x TLP attacks the stall directly.
// Per-wave reads 28 -> 20/phase; CU-phase LDS ~320KB within port budget.
// Grid 8192 = 16 ct x 512 rt, XCD-swizzled (bijective, 8192%8==0).
// ---------------------------------------------------------------------------
__launch_bounds__(256, 4)
__global__ void gemm_pool(const __half* __restrict__ Agb,
                          const __half* __restrict__ Qgb,
                          const uint4* __restrict__ W2g,
                          const float* __restrict__ pos,
                          const float* __restrict__ G0, const float* __restrict__ G1,
                          const float* __restrict__ c2, float* __restrict__ out) {
  __shared__ uint4 SH[2304];  // A dbuf [0,1024) | B dbuf [1024,2048) | Q [2048,2304)

  // bijective XCD swizzle: XCD x owns 1024 contiguous idx = 64 rt (4 frames:
  // ~512KB A+Q) x all 16 ct (1MB W2g) < 4MB L2/XCD.
  int wg  = blockIdx.x;
  int idx = (wg & 7) * 1024 + (wg >> 3);
  int rt  = idx >> 4;     // 0..511 (frame, i-quad)
  int ct  = idx & 15;     // d-64 tile
  int f = rt >> 4, i0 = (rt & 15) * 4;

  int t = threadIdx.x, lane = t & 63, w = t >> 6;
  int i = i0 + w;                     // this wave's i

  const uint4* aGL = (const uint4*)(Agb + (size_t)f * Pn * Mn) +
                     (size_t)(lane & 31) * 64 + (lane >> 5);
  const uint4* bGL = W2g + (size_t)(2 * ct) * 32 * 64 + lane;

  // stage phase p (K64): A 8 slots (ksl*2+jf), B 8 slots (ksl*2+nf);
  // wave w stages ksl=w (2 A + 2 B DMAs).
  auto stageAB = [&](int p) {
    int buf = p & 1;
    dma16(aGL + (size_t)0 * 2048 + (p * 4 + w) * 2, SH + buf * 512 + (w * 2 + 0) * 64);
    dma16(aGL + (size_t)1 * 2048 + (p * 4 + w) * 2, SH + buf * 512 + (w * 2 + 1) * 64);
    dma16(bGL + (0 * 32 + p * 4 + w) * 64, SH + 1024 + buf * 512 + (w * 2 + 0) * 64);
    dma16(bGL + (1 * 32 + p * 4 + w) * 64, SH + 1024 + buf * 512 + (w * 2 + 1) * 64);
  };

  // prologue: Q row for this wave's i (once; covers all 8 phases) + phase 0
  dma16((const uint4*)(Qgb + (size_t)(f * Pn + i) * Mn) + lane, SH + 2048 + w * 64);
  stageAB(0);

  f32x16 acc[2][2];  // [jf][nf]
#pragma unroll
  for (int jf = 0; jf < 2; ++jf)
#pragma unroll
    for (int nf = 0; nf < 2; ++nf)
      acc[jf][nf] = (f32x16){0.f,0.f,0.f,0.f,0.f,0.f,0.f,0.f,
                             0.f,0.f,0.f,0.f,0.f,0.f,0.f,0.f};

  int qb = 2048 + w * 64 + (lane >> 5);

#pragma unroll 1
  for (int p = 0; p < 8; ++p) {
    __syncthreads();                // buffer p ready (staged a full phase ago)
    if (p < 7) stageAB(p + 1);      // next phase's DMA overlaps this compute
    int ab = (p & 1) * 512 + lane;
    int bb = 1024 + (p & 1) * 512 + lane;

#pragma unroll
    for (int ksl = 0; ksl < 4; ++ksl) {
      int ks = p * 4 + ksl;
      uint4 a0 = SH[ab + (ksl * 2 + 0) * 64];
      uint4 a1 = SH[ab + (ksl * 2 + 1) * 64];
      uint4 q  = SH[qb + ks * 2];   // broadcast read (2 distinct addrs)
      f16x8 af0, af1;
      mk2(a0, a1, q, af0, af1);
      f16x8 bg0 = __builtin_bit_cast(f16x8, SH[bb + (ksl * 2 + 0) * 64]);
      f16x8 bg1 = __builtin_bit_cast(f16x8, SH[bb + (ksl * 2 + 1) * 64]);
      acc[0][0] = __builtin_amdgcn_mfma_f32_32x32x16_f16(af0, bg0, acc[0][0], 0, 0, 0);
      acc[1][0] = __builtin_amdgcn_mfma_f32_32x32x16_f16(af1, bg0, acc[1][0], 0, 0, 0);
      acc[0][1] = __builtin_amdgcn_mfma_f32_32x32x16_f16(af0, bg1, acc[0][1], 0, 0, 0);
      acc[1][1] = __builtin_amdgcn_mfma_f32_32x32x16_f16(af1, bg1, acc[1][1], 0, 0, 0);
    }
  }

  // ---- epilogue (in-wave): max over 64 j, then relu(S - R + c2) ----
  // C layout (32x32): col=lane&31 (d), row j = (reg&3)+8*(reg>>2)+4*(lane>>5).
  float px = pos[(f * Pn + i) * 2], py = pos[(f * Pn + i) * 2 + 1];
#pragma unroll
  for (int nf = 0; nf < 2; ++nf) {
    float mx = -3.0e38f;
#pragma unroll
    for (int jf = 0; jf < 2; ++jf)
#pragma unroll
      for (int rg = 0; rg < 16; ++rg)
        mx = fmaxf(mx, acc[jf][nf][rg]);
    mx = fmaxf(mx, __shfl_xor(mx, 32));
    if (lane < 32) {
      int d = ct * 64 + nf * 32 + (lane & 31);
      float r = px * G0[d] + py * G1[d];
      out[(f * Pn + i) * Dn + d] = fmaxf(mx - r + c2[d], 0.f);
    }
  }
}

// ---------------------------------------------------------------------------
extern "C" void kernel_launch(void* const* d_in, const int* in_sizes, int n_in,
                              void* d_out, int out_size, void* d_ws, size_t ws_size,
                              hipStream_t stream) {
  const float* hs    = (const float*)d_in[0];
  const float* pos   = (const float*)d_in[1];
  // d_in[2] seq_start_end: unused (equal-size frames, P=64)
  const float* We    = (const float*)d_in[3];
  const float* be    = (const float*)d_in[4];
  const float* W1    = (const float*)d_in[5];
  const float* b1    = (const float*)d_in[6];
  const float* g1    = (const float*)d_in[7];
  const float* beta1 = (const float*)d_in[8];
  const float* W2    = (const float*)d_in[9];
  const float* b2    = (const float*)d_in[10];
  const float* g2    = (const float*)d_in[11];
  const float* beta2 = (const float*)d_in[12];
  const float* rm1   = (const float*)d_in[13];
  const float* rv1   = (const float*)d_in[14];
  const float* rm2   = (const float*)d_in[15];
  const float* rv2   = (const float*)d_in[16];

  char* ws = (char*)d_ws;
  // layout: c2 4KB | G0 4KB | G1 4KB | Agb 2MB | Qgb 2MB | W2g 1MB
  float* c2 = (float*)(ws + 0);
  float* G0 = (float*)(ws + 4096);
  float* G1 = (float*)(ws + 8192);
  __half* Agb = (__half*)(ws + 12288);
  __half* Qgb = (__half*)(ws + 12288 + 2097152);
  uint4* W2g = (uint4*)(ws + 12288 + 2 * 2097152);
  float* out = (float*)d_out;

  prep_all<<<656, 512, 0, stream>>>(hs, pos, We, be, W1, b1, g1, beta1, rm1, rv1,
                                    W2, b2, g2, beta2, rm2, rv2, Agb, Qgb, W2g,
                                    G0, G1, c2);
  gemm_pool<<<8192, 256, 0, stream>>>(Agb, Qgb, W2g, pos, G0, G1, c2, out);
}

// Round 11
// 238.140 us; speedup vs baseline: 1.0379x; 1.0379x over previous
//
#include <hip/hip_runtime.h>
#include <hip/hip_fp16.h>
#include <stdint.h>

#define EPS_BN 1e-5f

constexpr int Fn = 32;    // frames
constexpr int Pn = 64;    // peds per frame
constexpr int Bn = 2048;  // batch
constexpr int Hn = 128;   // h_dim
constexpr int En = 64;    // embed dim
constexpr int Mn = 512;   // GEMM K
constexpr int Dn = 1024;  // GEMM N

using f16x8   = __attribute__((ext_vector_type(8))) _Float16;
using f32x16  = __attribute__((ext_vector_type(16))) float;

static __device__ __forceinline__ unsigned short hfbits(float f) {
  return __builtin_bit_cast(unsigned short, __float2half(f));
}

// async 16B/lane global -> LDS (LDS base wave-uniform; HW adds lane*16)
static __device__ __forceinline__ void dma16(const uint4* g, const uint4* l) {
  __builtin_amdgcn_global_load_lds(
      (const __attribute__((address_space(1))) unsigned int*)g,
      (__attribute__((address_space(3))) unsigned int*)l, 16, 0, 0);
}

// packed fp16 max: one VOP3P instruction (ROCm header lacks __hmax2)
static __device__ __forceinline__ uint32_t pkmax(uint32_t a, uint32_t b) {
  uint32_t r;
  asm("v_pk_max_f16 %0, %1, %2" : "=v"(r) : "v"(a), "v"(b));
  return r;
}

// r0/r1 = fp16 max(a0,q), max(a1,q): 8 instructions total.
static __device__ __forceinline__ void mk2(uint4 a0, uint4 a1, uint4 q,
                                           f16x8& r0, f16x8& r1) {
  uint4 x0, x1;
#pragma unroll
  for (int v = 0; v < 4; ++v) {
    uint32_t qw = ((const uint32_t*)&q)[v];
    ((uint32_t*)&x0)[v] = pkmax(((const uint32_t*)&a0)[v], qw);
    ((uint32_t*)&x1)[v] = pkmax(((const uint32_t*)&a1)[v], qw);
  }
  r0 = __builtin_bit_cast(f16x8, x0);
  r1 = __builtin_bit_cast(f16x8, x1);
}

// ---------------------------------------------------------------------------
// prep_all: 656 blocks x 512 threads (R4 version, unchanged).
// ---------------------------------------------------------------------------
__global__ void prep_all(const float* __restrict__ hs, const float* __restrict__ pos,
                         const float* __restrict__ We, const float* __restrict__ be,
                         const float* __restrict__ W1, const float* __restrict__ b1,
                         const float* __restrict__ g1, const float* __restrict__ beta1,
                         const float* __restrict__ rm1, const float* __restrict__ rv1,
                         const float* __restrict__ W2, const float* __restrict__ b2,
                         const float* __restrict__ g2, const float* __restrict__ beta2,
                         const float* __restrict__ rm2, const float* __restrict__ rv2,
                         __half* __restrict__ Agb, __half* __restrict__ Qgb,
                         uint4* __restrict__ W2g, float* __restrict__ G0,
                         float* __restrict__ G1, float* __restrict__ c2) {
  __shared__ float smem[64 * 65];
  int bid = blockIdx.x, t = threadIdx.x;
  if (bid < 512) {
    // ---- Ag/Qg for 4 batch rows, no LDS ----
    int rb = bid * 4, m = t;
    float w0 = 0.f, w1 = 0.f, c = 0.f;
    for (int e = 0; e < En; ++e) {
      float w = W1[e * Mn + m];
      w0 += We[e] * w; w1 += We[En + e] * w; c += be[e] * w;
    }
    c += b1[m];
    float s  = g1[m] * rsqrtf(rv1[m] + EPS_BN);
    float tt = beta1[m] - rm1[m] * s;
    float acc[4];
#pragma unroll
    for (int ri = 0; ri < 4; ++ri) acc[ri] = c;
#pragma unroll 4
    for (int e = 0; e < Hn; ++e) {
      float w = W1[(En + e) * Mn + m];
#pragma unroll
      for (int ri = 0; ri < 4; ++ri)
        acc[ri] += hs[(rb + ri) * Hn + e] * w;   // uniform addr -> s_load
    }
#pragma unroll
    for (int ri = 0; ri < 4; ++ri) {
      float q = pos[(rb + ri) * 2] * w0 + pos[(rb + ri) * 2 + 1] * w1;  // uniform
      Agb[(rb + ri) * Mn + m] = __float2half((acc[ri] + q) * s + tt);
      Qgb[(rb + ri) * Mn + m] = __float2half(q * s);
    }
  } else if (bid < 640) {
    // ---- W2 -> 32-col B-fragment granules (s2 folded), fp16 ----
    int b2i = bid - 512;                 // 0..127
    int d0 = (b2i & 15) * 64, k0 = (b2i >> 4) * 64;
    int col = t & 63, row8 = t >> 6;
#pragma unroll
    for (int rr = 0; rr < 8; ++rr) {
      int row = rr * 8 + row8;
      smem[row * 65 + col] = W2[(k0 + row) * Dn + d0 + col];  // [k_local][d_local]
    }
    __syncthreads();
    int lane = t & 63, q8 = t >> 6;
    int sel_n = q8 & 1, sel_ks = q8 >> 1;
    int dl = sel_n * 32 + (lane & 31), d = d0 + dl;
    float sf = g2[d] * rsqrtf(rv2[d] + EPS_BN);
    int kb = sel_ks * 16 + (lane >> 5) * 8;
    uint32_t wd[4];
#pragma unroll
    for (int h = 0; h < 4; ++h) {
      uint32_t u0 = hfbits(smem[(kb + 2 * h) * 65 + dl] * sf);
      uint32_t u1 = hfbits(smem[(kb + 2 * h + 1) * 65 + dl] * sf);
      wd[h] = u0 | (u1 << 16);
    }
    int n32 = (d0 >> 5) + sel_n;
    int ks  = (k0 >> 4) + sel_ks;
    W2g[(n32 * 32 + ks) * 64 + lane] = (uint4){wd[0], wd[1], wd[2], wd[3]};
  } else {
    // ---- G slice (64 d-cols) + c2 ----
    int gb = bid - 640;           // 0..15
    int d0g = gb * 64;
    float* wr0 = smem;            // [0,512)
    float* wr1 = smem + 512;      // [512,1024)
    {
      int m = t;
      float w0 = 0.f, w1 = 0.f;
      for (int e = 0; e < En; ++e) {
        float w = W1[e * Mn + m];
        w0 += We[e] * w; w1 += We[En + e] * w;
      }
      float s = g1[m] * rsqrtf(rv1[m] + EPS_BN);
      wr0[m] = w0 * s; wr1[m] = w1 * s;
    }
    __syncthreads();
    int dl = t & 63, part = t >> 6;   // 8 m-parts x 64 d
    float p0 = 0.f, p1 = 0.f;
#pragma unroll 4
    for (int mm = 0; mm < 64; ++mm) {
      int m = part * 64 + mm;
      float wv = W2[m * Dn + d0g + dl];
      p0 += wr0[m] * wv; p1 += wr1[m] * wv;
    }
    float* pr = smem + 1024;
    pr[part * 64 + dl] = p0;
    pr[512 + part * 64 + dl] = p1;
    __syncthreads();
    if (t < 128) {
      int which = t >> 6, dd = d0g + (t & 63);
      float s2v = g2[dd] * rsqrtf(rv2[dd] + EPS_BN);
      float sum = 0.f;
#pragma unroll
      for (int pp = 0; pp < 8; ++pp) sum += pr[which * 512 + pp * 64 + (t & 63)];
      (which ? G1 : G0)[dd] = sum * s2v;
      if (which == 0) c2[dd] = b2[dd] * s2v + beta2[dd] - rm2[dd] * s2v;
    }
  }
}

// read-set for one ksl: 7 uint4 = 28 VGPR (static member access only, rule #20)
struct RS { uint4 a0, a1, q, b0, b1, b2, b3; };

// ---------------------------------------------------------------------------
// gemm_pool R11: R4 tile/schedule EXACTLY (4i x 64j x 128d, 2 waves/SIMD,
// 2-buf __syncthreads, XCD swizzle, grid 4096) + explicit 1-ksl-ahead
// REGISTER ROTATION in the K-loop. R4's VGPR=84 proves the compiler held only
// ~one ksl's reads in flight: per ksl it ran issue-7-reads -> lgkm wait
// (~120cy) -> pkmax -> 8 MFMA (256cy), ~430cy serial per 256cy of MFMA (the
// ~50% MfmaUtil plateau that R3/R8/R9/R10 grafts never touched). Two named
// sets rA/rB alternate: each MFMA cluster covers the NEXT ksl's reads.
// Transient +28 VGPR (~112 <= 128 budget at 2 waves/SIMD, acc=128 AGPR).
// ---------------------------------------------------------------------------
__launch_bounds__(256, 2)
__global__ void gemm_pool(const __half* __restrict__ Agb,
                          const __half* __restrict__ Qgb,
                          const uint4* __restrict__ W2g,
                          const float* __restrict__ pos,
                          const float* __restrict__ G0, const float* __restrict__ G1,
                          const float* __restrict__ c2, float* __restrict__ out) {
  __shared__ uint4 SH[3328];  // A dbuf [0,1024) | B dbuf [1024,3072) | Q [3072,3328)

  // bijective XCD swizzle (nwg=4096, 8 XCDs): XCD x owns a contiguous rt chunk.
  int wg  = blockIdx.x;
  int swz = (wg & 7) * 512 + (wg >> 3);
  int ct  = swz & 7;     // d-128 tile
  int rt  = swz >> 3;    // (frame, i-quad)
  int f = rt >> 4, i0 = (rt & 15) * 4;

  int t = threadIdx.x, lane = t & 63, w = t >> 6;
  int i = i0 + w;                     // this wave's i

  const uint4* aGL = (const uint4*)(Agb + (size_t)f * Pn * Mn) +
                     (size_t)(lane & 31) * 64 + (lane >> 5);
  const uint4* bGL = W2g + (size_t)(4 * ct) * 32 * 64 + lane;

  // stage phase p (K64): A 8 slots (ksl*2+jf), B 16 slots (ksl*4+nf)
  auto stageAB = [&](int p) {
    int buf = p & 1;
    dma16(aGL + (size_t)0 * 2048 + (p * 4 + w) * 2, SH + buf * 512 + (w * 2 + 0) * 64);
    dma16(aGL + (size_t)1 * 2048 + (p * 4 + w) * 2, SH + buf * 512 + (w * 2 + 1) * 64);
#pragma unroll
    for (int nf = 0; nf < 4; ++nf)
      dma16(bGL + (nf * 32 + p * 4 + w) * 64,
            SH + 1024 + buf * 1024 + (w * 4 + nf) * 64);
  };

  // prologue: Q row for this wave's i (once) + phase 0 A/B
  dma16((const uint4*)(Qgb + (size_t)(f * Pn + i) * Mn) + lane, SH + 3072 + w * 64);
  stageAB(0);

  f32x16 acc[2][4];  // [jf][nf]
#pragma unroll
  for (int jf = 0; jf < 2; ++jf)
#pragma unroll
    for (int nf = 0; nf < 4; ++nf)
      acc[jf][nf] = (f32x16){0.f,0.f,0.f,0.f,0.f,0.f,0.f,0.f,
                             0.f,0.f,0.f,0.f,0.f,0.f,0.f,0.f};

  int qb = 3072 + w * 64 + (lane >> 5);

  // load one ksl's read-set (7 ds_read_b128, all addresses static per ksl)
  auto ldrs = [&](int ab, int bb, int p, int ksl) {
    RS r;
    r.a0 = SH[ab + (ksl * 2 + 0) * 64];
    r.a1 = SH[ab + (ksl * 2 + 1) * 64];
    r.q  = SH[qb + (p * 4 + ksl) * 2];
    r.b0 = SH[bb + (ksl * 4 + 0) * 64];
    r.b1 = SH[bb + (ksl * 4 + 1) * 64];
    r.b2 = SH[bb + (ksl * 4 + 2) * 64];
    r.b3 = SH[bb + (ksl * 4 + 3) * 64];
    return r;
  };
  // consume one read-set: 16 pkmax + 8 MFMA
  auto consume = [&](const RS& r) {
    f16x8 af0, af1;
    mk2(r.a0, r.a1, r.q, af0, af1);
    f16x8 bf0 = __builtin_bit_cast(f16x8, r.b0);
    f16x8 bf1 = __builtin_bit_cast(f16x8, r.b1);
    f16x8 bf2 = __builtin_bit_cast(f16x8, r.b2);
    f16x8 bf3 = __builtin_bit_cast(f16x8, r.b3);
    acc[0][0] = __builtin_amdgcn_mfma_f32_32x32x16_f16(af0, bf0, acc[0][0], 0, 0, 0);
    acc[1][0] = __builtin_amdgcn_mfma_f32_32x32x16_f16(af1, bf0, acc[1][0], 0, 0, 0);
    acc[0][1] = __builtin_amdgcn_mfma_f32_32x32x16_f16(af0, bf1, acc[0][1], 0, 0, 0);
    acc[1][1] = __builtin_amdgcn_mfma_f32_32x32x16_f16(af1, bf1, acc[1][1], 0, 0, 0);
    acc[0][2] = __builtin_amdgcn_mfma_f32_32x32x16_f16(af0, bf2, acc[0][2], 0, 0, 0);
    acc[1][2] = __builtin_amdgcn_mfma_f32_32x32x16_f16(af1, bf2, acc[1][2], 0, 0, 0);
    acc[0][3] = __builtin_amdgcn_mfma_f32_32x32x16_f16(af0, bf3, acc[0][3], 0, 0, 0);
    acc[1][3] = __builtin_amdgcn_mfma_f32_32x32x16_f16(af1, bf3, acc[1][3], 0, 0, 0);
  };

#pragma unroll 1
  for (int p = 0; p < 8; ++p) {
    __syncthreads();                // buffer p ready (staged a full phase ago)
    if (p < 7) stageAB(p + 1);      // next phase's DMA overlaps this compute
    int ab = (p & 1) * 512 + lane;
    int bb = 1024 + (p & 1) * 1024 + lane;

    // 1-ahead rotation: each consume's 8-MFMA cluster (256cy) hides the
    // next ksl's 7 ds_read issues + latency. Named sets, no dynamic index.
    RS rA = ldrs(ab, bb, p, 0);
    RS rB = ldrs(ab, bb, p, 1);
    consume(rA);
    rA = ldrs(ab, bb, p, 2);
    consume(rB);
    rB = ldrs(ab, bb, p, 3);
    consume(rA);
    consume(rB);
  }

  // ---- epilogue (in-wave): max over 64 j, then relu(S - R + c2) ----
  // C layout (32x32): col=lane&31, row=(reg&3)+8*(reg>>2)+4*(lane>>5).
  float px = pos[(f * Pn + i) * 2], py = pos[(f * Pn + i) * 2 + 1];
#pragma unroll
  for (int nf = 0; nf < 4; ++nf) {
    float mx = -3.0e38f;
#pragma unroll
    for (int jf = 0; jf < 2; ++jf)
#pragma unroll
      for (int rg = 0; rg < 16; ++rg)
        mx = fmaxf(mx, acc[jf][nf][rg]);
    mx = fmaxf(mx, __shfl_xor(mx, 32));
    if (lane < 32) {
      int d = ct * 128 + nf * 32 + (lane & 31);
      float r = px * G0[d] + py * G1[d];
      out[(f * Pn + i) * Dn + d] = fmaxf(mx - r + c2[d], 0.f);
    }
  }
}

// ---------------------------------------------------------------------------
extern "C" void kernel_launch(void* const* d_in, const int* in_sizes, int n_in,
                              void* d_out, int out_size, void* d_ws, size_t ws_size,
                              hipStream_t stream) {
  const float* hs    = (const float*)d_in[0];
  const float* pos   = (const float*)d_in[1];
  // d_in[2] seq_start_end: unused (equal-size frames, P=64)
  const float* We    = (const float*)d_in[3];
  const float* be    = (const float*)d_in[4];
  const float* W1    = (const float*)d_in[5];
  const float* b1    = (const float*)d_in[6];
  const float* g1    = (const float*)d_in[7];
  const float* beta1 = (const float*)d_in[8];
  const float* W2    = (const float*)d_in[9];
  const float* b2    = (const float*)d_in[10];
  const float* g2    = (const float*)d_in[11];
  const float* beta2 = (const float*)d_in[12];
  const float* rm1   = (const float*)d_in[13];
  const float* rv1   = (const float*)d_in[14];
  const float* rm2   = (const float*)d_in[15];
  const float* rv2   = (const float*)d_in[16];

  char* ws = (char*)d_ws;
  // layout: c2 4KB | G0 4KB | G1 4KB | Agb 2MB | Qgb 2MB | W2g 1MB
  float* c2 = (float*)(ws + 0);
  float* G0 = (float*)(ws + 4096);
  float* G1 = (float*)(ws + 8192);
  __half* Agb = (__half*)(ws + 12288);
  __half* Qgb = (__half*)(ws + 12288 + 2097152);
  uint4* W2g = (uint4*)(ws + 12288 + 2 * 2097152);
  float* out = (float*)d_out;

  prep_all<<<656, 512, 0, stream>>>(hs, pos, We, be, W1, b1, g1, beta1, rm1, rv1,
                                    W2, b2, g2, beta2, rm2, rv2, Agb, Qgb, W2g,
                                    G0, G1, c2);
  gemm_pool<<<4096, 256, 0, stream>>>(Agb, Qgb, W2g, pos, G0, G1, c2, out);
}

// Round 12
// 228.235 us; speedup vs baseline: 1.0830x; 1.0434x over previous
//
#include <hip/hip_runtime.h>
#include <hip/hip_fp16.h>
#include <stdint.h>

#define EPS_BN 1e-5f

constexpr int Fn = 32;    // frames
constexpr int Pn = 64;    // peds per frame
constexpr int Bn = 2048;  // batch
constexpr int Hn = 128;   // h_dim
constexpr int En = 64;    // embed dim
constexpr int Mn = 512;   // GEMM K
constexpr int Dn = 1024;  // GEMM N

using f16x8   = __attribute__((ext_vector_type(8))) _Float16;
using f32x16  = __attribute__((ext_vector_type(16))) float;

static __device__ __forceinline__ unsigned short hfbits(float f) {
  return __builtin_bit_cast(unsigned short, __float2half(f));
}

// async 16B/lane global -> LDS (LDS base wave-uniform; HW adds lane*16)
static __device__ __forceinline__ void dma16(const uint4* g, const uint4* l) {
  __builtin_amdgcn_global_load_lds(
      (const __attribute__((address_space(1))) unsigned int*)g,
      (__attribute__((address_space(3))) unsigned int*)l, 16, 0, 0);
}

// packed fp16 max: one VOP3P instruction (ROCm header lacks __hmax2)
static __device__ __forceinline__ uint32_t pkmax(uint32_t a, uint32_t b) {
  uint32_t r;
  asm("v_pk_max_f16 %0, %1, %2" : "=v"(r) : "v"(a), "v"(b));
  return r;
}

// r0/r1 = fp16 max(a0,q), max(a1,q): 8 instructions total.
static __device__ __forceinline__ void mk2(uint4 a0, uint4 a1, uint4 q,
                                           f16x8& r0, f16x8& r1) {
  uint4 x0, x1;
#pragma unroll
  for (int v = 0; v < 4; ++v) {
    uint32_t qw = ((const uint32_t*)&q)[v];
    ((uint32_t*)&x0)[v] = pkmax(((const uint32_t*)&a0)[v], qw);
    ((uint32_t*)&x1)[v] = pkmax(((const uint32_t*)&a1)[v], qw);
  }
  r0 = __builtin_bit_cast(f16x8, x0);
  r1 = __builtin_bit_cast(f16x8, x1);
}

// ---------------------------------------------------------------------------
// prep_all: 656 blocks x 512 threads (R4's best-measured prep).
// ---------------------------------------------------------------------------
__global__ void prep_all(const float* __restrict__ hs, const float* __restrict__ pos,
                         const float* __restrict__ We, const float* __restrict__ be,
                         const float* __restrict__ W1, const float* __restrict__ b1,
                         const float* __restrict__ g1, const float* __restrict__ beta1,
                         const float* __restrict__ rm1, const float* __restrict__ rv1,
                         const float* __restrict__ W2, const float* __restrict__ b2,
                         const float* __restrict__ g2, const float* __restrict__ beta2,
                         const float* __restrict__ rm2, const float* __restrict__ rv2,
                         __half* __restrict__ Agb, __half* __restrict__ Qgb,
                         uint4* __restrict__ W2g, float* __restrict__ G0,
                         float* __restrict__ G1, float* __restrict__ c2) {
  __shared__ float smem[64 * 65];
  int bid = blockIdx.x, t = threadIdx.x;
  if (bid < 512) {
    // ---- Ag/Qg for 4 batch rows, no LDS ----
    int rb = bid * 4, m = t;
    float w0 = 0.f, w1 = 0.f, c = 0.f;
    for (int e = 0; e < En; ++e) {
      float w = W1[e * Mn + m];
      w0 += We[e] * w; w1 += We[En + e] * w; c += be[e] * w;
    }
    c += b1[m];
    float s  = g1[m] * rsqrtf(rv1[m] + EPS_BN);
    float tt = beta1[m] - rm1[m] * s;
    float acc[4];
#pragma unroll
    for (int ri = 0; ri < 4; ++ri) acc[ri] = c;
#pragma unroll 4
    for (int e = 0; e < Hn; ++e) {
      float w = W1[(En + e) * Mn + m];
#pragma unroll
      for (int ri = 0; ri < 4; ++ri)
        acc[ri] += hs[(rb + ri) * Hn + e] * w;   // uniform addr -> s_load
    }
#pragma unroll
    for (int ri = 0; ri < 4; ++ri) {
      float q = pos[(rb + ri) * 2] * w0 + pos[(rb + ri) * 2 + 1] * w1;  // uniform
      Agb[(rb + ri) * Mn + m] = __float2half((acc[ri] + q) * s + tt);
      Qgb[(rb + ri) * Mn + m] = __float2half(q * s);
    }
  } else if (bid < 640) {
    // ---- W2 -> 32-col B-fragment granules (s2 folded), fp16 ----
    int b2i = bid - 512;                 // 0..127
    int d0 = (b2i & 15) * 64, k0 = (b2i >> 4) * 64;
    int col = t & 63, row8 = t >> 6;
#pragma unroll
    for (int rr = 0; rr < 8; ++rr) {
      int row = rr * 8 + row8;
      smem[row * 65 + col] = W2[(k0 + row) * Dn + d0 + col];  // [k_local][d_local]
    }
    __syncthreads();
    int lane = t & 63, q8 = t >> 6;
    int sel_n = q8 & 1, sel_ks = q8 >> 1;
    int dl = sel_n * 32 + (lane & 31), d = d0 + dl;
    float sf = g2[d] * rsqrtf(rv2[d] + EPS_BN);
    int kb = sel_ks * 16 + (lane >> 5) * 8;
    uint32_t wd[4];
#pragma unroll
    for (int h = 0; h < 4; ++h) {
      uint32_t u0 = hfbits(smem[(kb + 2 * h) * 65 + dl] * sf);
      uint32_t u1 = hfbits(smem[(kb + 2 * h + 1) * 65 + dl] * sf);
      wd[h] = u0 | (u1 << 16);
    }
    int n32 = (d0 >> 5) + sel_n;
    int ks  = (k0 >> 4) + sel_ks;
    W2g[(n32 * 32 + ks) * 64 + lane] = (uint4){wd[0], wd[1], wd[2], wd[3]};
  } else {
    // ---- G slice (64 d-cols) + c2 ----
    int gb = bid - 640;           // 0..15
    int d0g = gb * 64;
    float* wr0 = smem;            // [0,512)
    float* wr1 = smem + 512;      // [512,1024)
    {
      int m = t;
      float w0 = 0.f, w1 = 0.f;
      for (int e = 0; e < En; ++e) {
        float w = W1[e * Mn + m];
        w0 += We[e] * w; w1 += We[En + e] * w;
      }
      float s = g1[m] * rsqrtf(rv1[m] + EPS_BN);
      wr0[m] = w0 * s; wr1[m] = w1 * s;
    }
    __syncthreads();
    int dl = t & 63, part = t >> 6;   // 8 m-parts x 64 d
    float p0 = 0.f, p1 = 0.f;
#pragma unroll 4
    for (int mm = 0; mm < 64; ++mm) {
      int m = part * 64 + mm;
      float wv = W2[m * Dn + d0g + dl];
      p0 += wr0[m] * wv; p1 += wr1[m] * wv;
    }
    float* pr = smem + 1024;
    pr[part * 64 + dl] = p0;
    pr[512 + part * 64 + dl] = p1;
    __syncthreads();
    if (t < 128) {
      int which = t >> 6, dd = d0g + (t & 63);
      float s2v = g2[dd] * rsqrtf(rv2[dd] + EPS_BN);
      float sum = 0.f;
#pragma unroll
      for (int pp = 0; pp < 8; ++pp) sum += pr[which * 512 + pp * 64 + (t & 63)];
      (which ? G1 : G0)[dd] = sum * s2v;
      if (which == 0) c2[dd] = b2[dd] * s2v + beta2[dd] - rm2[dd] * s2v;
    }
  }
}

// ---------------------------------------------------------------------------
// gemm_pool: R2-EXACT (best measured: 128.4us, MfmaUtil 50, conflicts 0).
// 32x32x16 fp16 MFMA. Block = 4 i x 64 j x 128 d; wave = ONE i, all 64 j
// (2 jf), 4 n-granules -> 8 MFMA/kstep, 2 waves/SIMD (212 unified regs),
// 2 blocks/CU, 52KB LDS. A+B dbuf via global_load_lds; Q staged once;
// dim3(8,512) grid, no XCD swizzle (R2 vs R4 A/B: swizzle cut FETCH 17->6.2MB
// but cost ~2% time — L3 absorbs the refetch; measured-best wins).
// Plateau evidence (R3,R5,R7,R8,R9,R10,R11 all null-to-negative): this wave
// tile is the local optimum at acc=128 AGPR; 7 reads/8 pkmax/8 MFMA per ksl.
// ---------------------------------------------------------------------------
__launch_bounds__(256, 2)
__global__ void gemm_pool(const __half* __restrict__ Agb,
                          const __half* __restrict__ Qgb,
                          const uint4* __restrict__ W2g,
                          const float* __restrict__ pos,
                          const float* __restrict__ G0, const float* __restrict__ G1,
                          const float* __restrict__ c2, float* __restrict__ out) {
  __shared__ uint4 SH[3328];  // A dbuf [0,1024) | B dbuf [1024,3072) | Q [3072,3328)

  int ct = blockIdx.x;   // 0..7   d-128 tile
  int rt = blockIdx.y;   // 0..511 (frame, i-quad)
  int f = rt >> 4, i0 = (rt & 15) * 4;

  int t = threadIdx.x, lane = t & 63, w = t >> 6;
  int i = i0 + w;                     // this wave's i

  const uint4* aGL = (const uint4*)(Agb + (size_t)f * Pn * Mn) +
                     (size_t)(lane & 31) * 64 + (lane >> 5);
  const uint4* bGL = W2g + (size_t)(4 * ct) * 32 * 64 + lane;

  // stage phase p (K64): A 8 slots (ksl*2+jf), B 16 slots (ksl*4+nf)
  auto stageAB = [&](int p) {
    int buf = p & 1;
    dma16(aGL + (size_t)0 * 2048 + (p * 4 + w) * 2, SH + buf * 512 + (w * 2 + 0) * 64);
    dma16(aGL + (size_t)1 * 2048 + (p * 4 + w) * 2, SH + buf * 512 + (w * 2 + 1) * 64);
#pragma unroll
    for (int nf = 0; nf < 4; ++nf)
      dma16(bGL + (nf * 32 + p * 4 + w) * 64,
            SH + 1024 + buf * 1024 + (w * 4 + nf) * 64);
  };

  // prologue: Q row for this wave's i (once) + phase 0 A/B
  dma16((const uint4*)(Qgb + (size_t)(f * Pn + i) * Mn) + lane, SH + 3072 + w * 64);
  stageAB(0);

  f32x16 acc[2][4];  // [jf][nf]
#pragma unroll
  for (int jf = 0; jf < 2; ++jf)
#pragma unroll
    for (int nf = 0; nf < 4; ++nf)
      acc[jf][nf] = (f32x16){0.f,0.f,0.f,0.f,0.f,0.f,0.f,0.f,
                             0.f,0.f,0.f,0.f,0.f,0.f,0.f,0.f};

  int qb = 3072 + w * 64 + (lane >> 5);

#pragma unroll 1
  for (int p = 0; p < 8; ++p) {
    __syncthreads();                // buffer p ready (staged a full phase ago)
    if (p < 7) stageAB(p + 1);      // next phase's DMA overlaps this compute
    int ab = (p & 1) * 512 + lane;
    int bb = 1024 + (p & 1) * 1024 + lane;

#pragma unroll
    for (int ksl = 0; ksl < 4; ++ksl) {
      int ks = p * 4 + ksl;
      uint4 a0 = SH[ab + (ksl * 2 + 0) * 64];
      uint4 a1 = SH[ab + (ksl * 2 + 1) * 64];
      uint4 q  = SH[qb + ks * 2];   // broadcast read
      f16x8 af0, af1;
      mk2(a0, a1, q, af0, af1);
#pragma unroll
      for (int nf = 0; nf < 4; ++nf) {
        f16x8 bg = __builtin_bit_cast(f16x8, SH[bb + (ksl * 4 + nf) * 64]);
        acc[0][nf] = __builtin_amdgcn_mfma_f32_32x32x16_f16(af0, bg, acc[0][nf], 0, 0, 0);
        acc[1][nf] = __builtin_amdgcn_mfma_f32_32x32x16_f16(af1, bg, acc[1][nf], 0, 0, 0);
      }
    }
  }

  // ---- epilogue (in-wave): max over 64 j, then relu(S - R + c2) ----
  // C layout (32x32): col=lane&31, row=(reg&3)+8*(reg>>2)+4*(lane>>5).
  float px = pos[(f * Pn + i) * 2], py = pos[(f * Pn + i) * 2 + 1];
#pragma unroll
  for (int nf = 0; nf < 4; ++nf) {
    float mx = -3.0e38f;
#pragma unroll
    for (int jf = 0; jf < 2; ++jf)
#pragma unroll
      for (int rg = 0; rg < 16; ++rg)
        mx = fmaxf(mx, acc[jf][nf][rg]);
    mx = fmaxf(mx, __shfl_xor(mx, 32));
    if (lane < 32) {
      int d = ct * 128 + nf * 32 + (lane & 31);
      float r = px * G0[d] + py * G1[d];
      out[(f * Pn + i) * Dn + d] = fmaxf(mx - r + c2[d], 0.f);
    }
  }
}

// ---------------------------------------------------------------------------
extern "C" void kernel_launch(void* const* d_in, const int* in_sizes, int n_in,
                              void* d_out, int out_size, void* d_ws, size_t ws_size,
                              hipStream_t stream) {
  const float* hs    = (const float*)d_in[0];
  const float* pos   = (const float*)d_in[1];
  // d_in[2] seq_start_end: unused (equal-size frames, P=64)
  const float* We    = (const float*)d_in[3];
  const float* be    = (const float*)d_in[4];
  const float* W1    = (const float*)d_in[5];
  const float* b1    = (const float*)d_in[6];
  const float* g1    = (const float*)d_in[7];
  const float* beta1 = (const float*)d_in[8];
  const float* W2    = (const float*)d_in[9];
  const float* b2    = (const float*)d_in[10];
  const float* g2    = (const float*)d_in[11];
  const float* beta2 = (const float*)d_in[12];
  const float* rm1   = (const float*)d_in[13];
  const float* rv1   = (const float*)d_in[14];
  const float* rm2   = (const float*)d_in[15];
  const float* rv2   = (const float*)d_in[16];

  char* ws = (char*)d_ws;
  // layout: c2 4KB | G0 4KB | G1 4KB | Agb 2MB | Qgb 2MB | W2g 1MB
  float* c2 = (float*)(ws + 0);
  float* G0 = (float*)(ws + 4096);
  float* G1 = (float*)(ws + 8192);
  __half* Agb = (__half*)(ws + 12288);
  __half* Qgb = (__half*)(ws + 12288 + 2097152);
  uint4* W2g = (uint4*)(ws + 12288 + 2 * 2097152);
  float* out = (float*)d_out;

  prep_all<<<656, 512, 0, stream>>>(hs, pos, We, be, W1, b1, g1, beta1, rm1, rv1,
                                    W2, b2, g2, beta2, rm2, rv2, Agb, Qgb, W2g,
                                    G0, G1, c2);
  gemm_pool<<<dim3(8, 512), 256, 0, stream>>>(Agb, Qgb, W2g, pos, G0, G1, c2, out);
}